// Round 1
// baseline (140.112 us; speedup 1.0000x reference)
//
#include <hip/hip_runtime.h>
#include <cmath>

// Problem constants (fixed by the reference).
constexpr int Bn = 16, ICn = 16, OCn = 64, Kn = 3, Hn = 256, Wn = 256;
constexpr int NE  = ICn * Kn * Kn;   // 144 envelopes, one per (ic,kh,kw)
constexpr int CAP = 64;              // max hull lines per envelope
constexpr int LINES_OFF = 4096;      // byte offset of lines[] in workspace

// ---------------------------------------------------------------------------
// Kernel 1: build the exact lower envelope (convex-hull-trick) for each of the
// 144 (ic,kh,kw) line families {y = w[oc,ic,kh,kw]*x + bias[oc] : oc}.
// One wave (64 lanes) per envelope; lane = oc. Walk the envelope left->right:
// start at max-slope line, repeatedly take the nearest intersection with a
// smaller-slope line. Slope strictly decreases each step => <= 64 steps.
// Hull is a SUBSET of the original lines => min over hull == min over all 64
// for every real x (exact, no approximation).
// ---------------------------------------------------------------------------
__global__ void build_hulls(const float* __restrict__ weight,
                            const float* __restrict__ bias,
                            int* __restrict__ cnt,
                            float2* __restrict__ lines)
{
    int wave = (int)(threadIdx.x >> 6);
    int lane = (int)(threadIdx.x & 63);
    int e = blockIdx.x * 4 + wave;
    if (e >= NE) return;
    int ic = e / (Kn * Kn);
    int t  = e % (Kn * Kn);

    // lane's line: slope = w[lane, ic, kh, kw], intercept = bias[lane]
    double mm = (double)weight[((size_t)lane * ICn + ic) * (Kn * Kn) + t];
    double cc = (double)bias[lane];

    // initial envelope line at x -> -inf: max slope, tie -> min intercept
    double m_cur = mm, c_cur = cc;
    #pragma unroll
    for (int off = 32; off >= 1; off >>= 1) {
        double m2 = __shfl_xor(m_cur, off, 64);
        double c2 = __shfl_xor(c_cur, off, 64);
        if (m2 > m_cur || (m2 == m_cur && c2 < c_cur)) { m_cur = m2; c_cur = c2; }
    }

    float2* L = lines + (size_t)e * CAP;
    int n = 0;
    while (true) {
        if (lane == 0) L[n] = make_float2((float)m_cur, (float)c_cur);
        ++n;
        // nearest takeover point among strictly-smaller-slope lines
        double xi = 1e308, mi = 0.0, ci = 0.0;
        if (mm < m_cur) {
            xi = (cc - c_cur) / (m_cur - mm);   // denominator > 0
            mi = mm; ci = cc;
        }
        #pragma unroll
        for (int off = 32; off >= 1; off >>= 1) {
            double x2 = __shfl_xor(xi, off, 64);
            double m2 = __shfl_xor(mi, off, 64);
            double c2 = __shfl_xor(ci, off, 64);
            // min x; tie -> min slope (line that is lowest beyond the tie point)
            if (x2 < xi || (x2 == xi && (m2 < mi || (m2 == mi && c2 < ci)))) {
                xi = x2; mi = m2; ci = c2;
            }
        }
        if (xi > 1e307) break;        // no smaller-slope line remains
        m_cur = mi; c_cur = ci;
    }
    if (lane == 0) {
        float2 last = L[n - 1];
        int np = (n + 3) & ~3;        // pad count to x4 (duplicates are harmless)
        for (int p = n; p < np; ++p) L[p] = last;
        cnt[e] = np;
    }
}

// ---------------------------------------------------------------------------
// Kernel 2: per output pixel, min over the 144 envelopes evaluated at the
// corresponding (zero-padded) input taps, then tanh(tanh(.)).
// Hull line params are wave-uniform (indexed only by loop counters) -> the
// compiler can scalarize those loads; x loads are lane-coalesced along W.
// 4 independent accumulators break the fmin dependency chain.
// ---------------------------------------------------------------------------
__global__ __launch_bounds__(256) void fused_min_tanh(
    const float* __restrict__ x,
    const int* __restrict__ cnt,
    const float2* __restrict__ lines,
    float* __restrict__ out)
{
    int idx = blockIdx.x * 256 + (int)threadIdx.x;
    int w0 = idx & (Wn - 1);
    int h0 = (idx >> 8) & (Hn - 1);
    int b0 = idx >> 16;

    float a0 = 3.4e38f, a1 = 3.4e38f, a2 = 3.4e38f, a3 = 3.4e38f;

    const float* xb = x + ((size_t)b0 * ICn) * (Hn * Wn);
    for (int ic = 0; ic < ICn; ++ic) {
        const float* xc = xb + (size_t)ic * (Hn * Wn);
        // load the 3x3 window (END-padded with zeros, matching jnp.pad((0,K-1)))
        float xv[Kn * Kn];
        #pragma unroll
        for (int kh = 0; kh < Kn; ++kh) {
            int hh = h0 + kh;
            #pragma unroll
            for (int kw = 0; kw < Kn; ++kw) {
                int ww = w0 + kw;
                xv[kh * Kn + kw] = (hh < Hn && ww < Wn) ? xc[hh * Wn + ww] : 0.0f;
            }
        }
        #pragma unroll
        for (int t = 0; t < Kn * Kn; ++t) {
            int e = ic * (Kn * Kn) + t;
            int c = cnt[e];                       // uniform, multiple of 4
            const float2* L = lines + (size_t)e * CAP;
            float xt = xv[t];
            for (int p = 0; p < c; p += 4) {
                float2 l0 = L[p + 0];
                float2 l1 = L[p + 1];
                float2 l2 = L[p + 2];
                float2 l3 = L[p + 3];
                a0 = fminf(a0, fmaf(xt, l0.x, l0.y));
                a1 = fminf(a1, fmaf(xt, l1.x, l1.y));
                a2 = fminf(a2, fmaf(xt, l2.x, l2.y));
                a3 = fminf(a3, fmaf(xt, l3.x, l3.y));
            }
        }
    }
    float best = fminf(fminf(a0, a1), fminf(a2, a3));
    out[idx] = tanhf(tanhf(best));
}

// ---------------------------------------------------------------------------
// Fallback (only if the workspace is unexpectedly tiny): exact brute force.
// ---------------------------------------------------------------------------
__global__ __launch_bounds__(256) void brute_force(
    const float* __restrict__ x,
    const float* __restrict__ weight,
    const float* __restrict__ bias,
    float* __restrict__ out)
{
    int idx = blockIdx.x * 256 + (int)threadIdx.x;
    int w0 = idx & (Wn - 1);
    int h0 = (idx >> 8) & (Hn - 1);
    int b0 = idx >> 16;

    float best = 3.4e38f;
    const float* xb = x + ((size_t)b0 * ICn) * (Hn * Wn);
    for (int ic = 0; ic < ICn; ++ic) {
        const float* xc = xb + (size_t)ic * (Hn * Wn);
        #pragma unroll
        for (int kh = 0; kh < Kn; ++kh) {
            int hh = h0 + kh;
            #pragma unroll
            for (int kw = 0; kw < Kn; ++kw) {
                int ww = w0 + kw;
                float xvv = (hh < Hn && ww < Wn) ? xc[hh * Wn + ww] : 0.0f;
                for (int oc = 0; oc < OCn; ++oc) {
                    float wv = weight[((size_t)(oc * ICn + ic) * Kn + kh) * Kn + kw];
                    best = fminf(best, fmaf(xvv, wv, bias[oc]));
                }
            }
        }
    }
    out[idx] = tanhf(tanhf(best));
}

extern "C" void kernel_launch(void* const* d_in, const int* in_sizes, int n_in,
                              void* d_out, int out_size, void* d_ws, size_t ws_size,
                              hipStream_t stream)
{
    const float* x      = (const float*)d_in[0];
    const float* weight = (const float*)d_in[1];
    const float* bias   = (const float*)d_in[2];
    float* out = (float*)d_out;

    const size_t need = (size_t)LINES_OFF + (size_t)NE * CAP * sizeof(float2);
    const int npix = Bn * Hn * Wn;           // 1,048,576
    const int nblk = npix / 256;             // 4096

    if (ws_size >= need) {
        int*    cnt   = (int*)d_ws;
        float2* lines = (float2*)((char*)d_ws + LINES_OFF);
        build_hulls<<<dim3(NE / 4), dim3(256), 0, stream>>>(weight, bias, cnt, lines);
        fused_min_tanh<<<dim3(nblk), dim3(256), 0, stream>>>(x, cnt, lines, out);
    } else {
        brute_force<<<dim3(nblk), dim3(256), 0, stream>>>(x, weight, bias, out);
    }
}

// Round 2
// 93.279 us; speedup vs baseline: 1.5021x; 1.5021x over previous
//
#include <hip/hip_runtime.h>
#include <cmath>

// Problem constants (fixed by the reference).
constexpr int Bn = 16, ICn = 16, OCn = 64, Kn = 3, Hn = 256, Wn = 256;
constexpr int NE  = ICn * Kn * Kn;   // 144 envelopes, one per (ic,kh,kw)
constexpr int CAP = 64;              // max hull lines per envelope
constexpr int LINES_OFF = 4096;      // byte offset of lines[] in workspace
constexpr int DUMMY_OFF = 2048;      // safe readable scratch for tail-lane loads

// ---------------------------------------------------------------------------
// Kernel 1: build the exact lower envelope (convex-hull-trick) for each of the
// 144 (ic,kh,kw) line families {y = w[oc,ic,kh,kw]*x + bias[oc] : oc}.
// One wave (64 lanes) per envelope; lane = oc. Walk the envelope left->right:
// start at max-slope line, repeatedly take the nearest intersection with a
// smaller-slope line. Slope strictly decreases each step => <= 64 steps.
// Hull is a SUBSET of the original lines => min over hull == min over all 64
// for every real x (exact, no approximation).
// ---------------------------------------------------------------------------
__global__ void build_hulls(const float* __restrict__ weight,
                            const float* __restrict__ bias,
                            int* __restrict__ cnt,
                            float2* __restrict__ lines)
{
    int wave = (int)(threadIdx.x >> 6);
    int lane = (int)(threadIdx.x & 63);
    int e = blockIdx.x * 4 + wave;
    if (e >= NE) return;
    int ic = e / (Kn * Kn);
    int t  = e % (Kn * Kn);

    // lane's line: slope = w[lane, ic, kh, kw], intercept = bias[lane]
    double mm = (double)weight[((size_t)lane * ICn + ic) * (Kn * Kn) + t];
    double cc = (double)bias[lane];

    // initial envelope line at x -> -inf: max slope, tie -> min intercept
    double m_cur = mm, c_cur = cc;
    #pragma unroll
    for (int off = 32; off >= 1; off >>= 1) {
        double m2 = __shfl_xor(m_cur, off, 64);
        double c2 = __shfl_xor(c_cur, off, 64);
        if (m2 > m_cur || (m2 == m_cur && c2 < c_cur)) { m_cur = m2; c_cur = c2; }
    }

    float2* L = lines + (size_t)e * CAP;
    int n = 0;
    while (true) {
        if (lane == 0) L[n] = make_float2((float)m_cur, (float)c_cur);
        ++n;
        // nearest takeover point among strictly-smaller-slope lines
        double xi = 1e308, mi = 0.0, ci = 0.0;
        if (mm < m_cur) {
            xi = (cc - c_cur) / (m_cur - mm);   // denominator > 0
            mi = mm; ci = cc;
        }
        #pragma unroll
        for (int off = 32; off >= 1; off >>= 1) {
            double x2 = __shfl_xor(xi, off, 64);
            double m2 = __shfl_xor(mi, off, 64);
            double c2 = __shfl_xor(ci, off, 64);
            // min x; tie -> min slope (line that is lowest beyond the tie point)
            if (x2 < xi || (x2 == xi && (m2 < mi || (m2 == mi && c2 < ci)))) {
                xi = x2; mi = m2; ci = c2;
            }
        }
        if (xi > 1e307) break;        // no smaller-slope line remains
        m_cur = mi; c_cur = ci;
    }
    if (lane == 0) {
        float2 last = L[n - 1];
        int np = (n + 3) & ~3;        // pad count to x4 (duplicates are harmless)
        for (int p = n; p < np; ++p) L[p] = last;
        cnt[e] = np;
    }
}

// ---------------------------------------------------------------------------
// Kernel 2: 4 horizontally-adjacent pixels per thread. Per ic we load the
// shared 3x6 window patch once (float4 + float2 per row; tail lane w0==252
// reads a dummy and zeroes via select). Per 4 hull lines: 2 uniform dwordx4
// loads (L1-broadcast) + 16 fma + 8 min3 for 16 pixel-line evaluations.
// ---------------------------------------------------------------------------
__global__ __launch_bounds__(256) void fused_min_tanh4(
    const float* __restrict__ x,
    const int* __restrict__ cnt,
    const float4* __restrict__ lines4,   // (m0,b0,m1,b1) pairs
    const float* __restrict__ dummy,     // safe readable scratch
    float* __restrict__ out)
{
    const int t  = (int)threadIdx.x;
    const int w0 = (t & 63) << 2;        // 4-pixel tile start along W
    const int hr = t >> 6;               // 0..3 row within the block's h-band
    const int hb = (int)blockIdx.x & 63; // h-band index
    const int b0 = (int)blockIdx.x >> 6; // batch
    const int h  = hb * 4 + hr;          // wave-uniform

    const bool tail = (w0 == 252);       // cols w0+4,w0+5 would be 256,257

    float a0[4], a1[4];
    #pragma unroll
    for (int p = 0; p < 4; ++p) { a0[p] = 3.4e38f; a1[p] = 3.4e38f; }

    const float* xb = x + (size_t)b0 * (ICn * Hn * Wn);

    for (int ic = 0; ic < ICn; ++ic) {
        const float* xc = xb + ic * (Hn * Wn);
        // shared window patch: rows h..h+2 (end-padded), cols w0..w0+5
        float r[3][6];
        #pragma unroll
        for (int kh = 0; kh < 3; ++kh) {
            const int hh = h + kh;
            if (hh < Hn) {               // wave-uniform branch
                const float* rp = xc + hh * Wn;
                const float4 A  = *reinterpret_cast<const float4*>(rp + w0);
                const float2 Bv = *reinterpret_cast<const float2*>(
                                      tail ? dummy : (rp + w0 + 4));
                r[kh][0] = A.x; r[kh][1] = A.y; r[kh][2] = A.z; r[kh][3] = A.w;
                r[kh][4] = tail ? 0.0f : Bv.x;
                r[kh][5] = tail ? 0.0f : Bv.y;
            } else {
                #pragma unroll
                for (int j = 0; j < 6; ++j) r[kh][j] = 0.0f;
            }
        }
        #pragma unroll
        for (int kh = 0; kh < 3; ++kh) {
            #pragma unroll
            for (int kw = 0; kw < 3; ++kw) {
                const int e = (ic * 3 + kh) * 3 + kw;
                const int c = cnt[e];                 // uniform, multiple of 4
                const float4* L = lines4 + (size_t)e * (CAP / 2);
                const float x0 = r[kh][kw + 0];
                const float x1 = r[kh][kw + 1];
                const float x2 = r[kh][kw + 2];
                const float x3 = r[kh][kw + 3];
                for (int p = 0; p < c; p += 4) {
                    const float4 u = L[0];
                    const float4 v = L[1];
                    L += 2;
                    a0[0] = fminf(a0[0], fminf(fmaf(x0, u.x, u.y), fmaf(x0, u.z, u.w)));
                    a0[1] = fminf(a0[1], fminf(fmaf(x1, u.x, u.y), fmaf(x1, u.z, u.w)));
                    a0[2] = fminf(a0[2], fminf(fmaf(x2, u.x, u.y), fmaf(x2, u.z, u.w)));
                    a0[3] = fminf(a0[3], fminf(fmaf(x3, u.x, u.y), fmaf(x3, u.z, u.w)));
                    a1[0] = fminf(a1[0], fminf(fmaf(x0, v.x, v.y), fmaf(x0, v.z, v.w)));
                    a1[1] = fminf(a1[1], fminf(fmaf(x1, v.x, v.y), fmaf(x1, v.z, v.w)));
                    a1[2] = fminf(a1[2], fminf(fmaf(x2, v.x, v.y), fmaf(x2, v.z, v.w)));
                    a1[3] = fminf(a1[3], fminf(fmaf(x3, v.x, v.y), fmaf(x3, v.z, v.w)));
                }
            }
        }
    }

    float4 o;
    o.x = tanhf(tanhf(fminf(a0[0], a1[0])));
    o.y = tanhf(tanhf(fminf(a0[1], a1[1])));
    o.z = tanhf(tanhf(fminf(a0[2], a1[2])));
    o.w = tanhf(tanhf(fminf(a0[3], a1[3])));
    *reinterpret_cast<float4*>(out + (((size_t)b0 * Hn + h) * Wn + w0)) = o;
}

// ---------------------------------------------------------------------------
// Fallback (only if the workspace is unexpectedly tiny): exact brute force.
// ---------------------------------------------------------------------------
__global__ __launch_bounds__(256) void brute_force(
    const float* __restrict__ x,
    const float* __restrict__ weight,
    const float* __restrict__ bias,
    float* __restrict__ out)
{
    int idx = blockIdx.x * 256 + (int)threadIdx.x;
    int w0 = idx & (Wn - 1);
    int h0 = (idx >> 8) & (Hn - 1);
    int b0 = idx >> 16;

    float best = 3.4e38f;
    const float* xb = x + ((size_t)b0 * ICn) * (Hn * Wn);
    for (int ic = 0; ic < ICn; ++ic) {
        const float* xc = xb + (size_t)ic * (Hn * Wn);
        #pragma unroll
        for (int kh = 0; kh < Kn; ++kh) {
            int hh = h0 + kh;
            #pragma unroll
            for (int kw = 0; kw < Kn; ++kw) {
                int ww = w0 + kw;
                float xvv = (hh < Hn && ww < Wn) ? xc[hh * Wn + ww] : 0.0f;
                for (int oc = 0; oc < OCn; ++oc) {
                    float wv = weight[((size_t)(oc * ICn + ic) * Kn + kh) * Kn + kw];
                    best = fminf(best, fmaf(xvv, wv, bias[oc]));
                }
            }
        }
    }
    out[idx] = tanhf(tanhf(best));
}

extern "C" void kernel_launch(void* const* d_in, const int* in_sizes, int n_in,
                              void* d_out, int out_size, void* d_ws, size_t ws_size,
                              hipStream_t stream)
{
    const float* x      = (const float*)d_in[0];
    const float* weight = (const float*)d_in[1];
    const float* bias   = (const float*)d_in[2];
    float* out = (float*)d_out;

    const size_t need = (size_t)LINES_OFF + (size_t)NE * CAP * sizeof(float2);
    const int npix = Bn * Hn * Wn;           // 1,048,576

    if (ws_size >= need) {
        int*    cnt   = (int*)d_ws;
        float2* lines = (float2*)((char*)d_ws + LINES_OFF);
        const float* dummy = (const float*)((char*)d_ws + DUMMY_OFF);
        build_hulls<<<dim3(NE / 4), dim3(256), 0, stream>>>(weight, bias, cnt, lines);
        // 4 px/thread: 1024 blocks x 256 threads x 4 px = 1,048,576 pixels
        fused_min_tanh4<<<dim3(Bn * Hn / 4), dim3(256), 0, stream>>>(
            x, cnt, (const float4*)lines, dummy, out);
    } else {
        brute_force<<<dim3(npix / 256), dim3(256), 0, stream>>>(x, weight, bias, out);
    }
}